// Round 6
// baseline (548.236 us; speedup 1.0000x reference)
//
#include <hip/hip_runtime.h>
#include <hip/hip_bf16.h>

// Fused Conv3d(3->16,k=3,valid) + conv_b + ReLU + maxpool2x2x2
// + spatial mean(fp32) + /2 + bias + channel-sum  ->  out[32] fp32.
//
// R15: occupancy/overlap — 256-thread blocks, w-split in half.
//  Diagnosis: pipe budgets (MFMA ~28us/SIMD at 32cyc/SIMD per mfma, VALU
//  ~14us, LDS ~31us) sum serialized to the measured ~93us because only 2
//  independent 8-wave barrier groups/CU exist (39% occ) — phases lockstep.
//  Fix: block = (hp, ws, b), 4 waves, LDS 2x8448B, <=64 VGPR -> 8 blocks
//  x 4 waves = 32 waves/CU, 8 independent barrier groups; pipes overlap.
//  - ws=0: input w 0..65 (rows 64,65 = halo, staged by 16 threads from 3
//    prefetched scalars); ws=1: input w 64..127 (rows 64,65 zeroed once;
//    only reach masked outputs). Validity mask gains ws*32 term.
//  - XCD bijective swizzle: 4032 = 8 x 504.
// (R12 core kept verbatim, verified absmax=0 twice): operand-swapped MFMA
//  (M=spatial, N=(ch,dd)), in-register 2x2 pool + DPP dd-pool, d-plane
//  rotation (stage 2 planes/iter, parity ^16, hs-split buffer), ci-fast
//  packing, XOR bank swizzle, lgkm-only BAR (globals stay in flight).
//  MFMA m32n32k16, D: col=lane&31, row=(reg&3)+8*(reg>>2)+4*(lane>>5).

typedef __attribute__((ext_vector_type(8)))  short  short8;
typedef __attribute__((ext_vector_type(2)))  float  floatx2;
typedef __attribute__((ext_vector_type(4)))  float  floatx4;
typedef __attribute__((ext_vector_type(16))) float  floatx16;

__device__ __forceinline__ short f2bf(float f) {
    unsigned u = __builtin_bit_cast(unsigned, f);
    unsigned r = (u + 0x7FFFu + ((u >> 16) & 1u)) >> 16;
    return (short)r;
}

__device__ __forceinline__ unsigned pkbf2(float a, float b) {
    __hip_bfloat162 h = __float22bfloat162_rn(float2{a, b});  // v_cvt_pk_bf16_f32
    unsigned r;
    __builtin_memcpy(&r, &h, 4);
    return r;
}

template <int CTRL>
__device__ __forceinline__ float dpp_max(float v) {
    int x = __builtin_bit_cast(int, v);
    int y = __builtin_amdgcn_mov_dpp(x, CTRL, 0xF, 0xF, true);
    return fmaxf(v, __builtin_bit_cast(float, y));
}

// LDS-only barrier: drain DS ops, leave global loads in flight (no vmcnt).
#define BAR() asm volatile("s_waitcnt lgkmcnt(0)\n\ts_barrier" ::: "memory")

#define BUFSZ 8448   // 66 rows x 128 B

// ---- init: wtab[f=kh*3+kw][lane][8] zero-padded B-frags + out = bias sums ----
__global__ void init_kernel(const float* __restrict__ wg,
                            const float* __restrict__ biasg,
                            short* __restrict__ wtab,   // d_ws: 9*64*8 bf16 = 9216 B
                            float* __restrict__ out)    // [32]
{
    const int t = threadIdx.x;               // 0..575
    if (t < 576) {
        const int lane = t & 63, f = t >> 6;
        const int kh = f / 3, kw = f % 3;
        const int m = lane & 31, hs = lane >> 5;
        const int ch = m >> 1, dd = m & 1;   // col = 2*ch + dd
        short8 v;
        #pragma unroll
        for (int j = 0; j < 8; ++j) {
            const int s = hs * 8 + j;        // k-slot: dl_rel = s>>2, ci = s&3
            const int dl = s >> 2, ci = s & 3;
            const int kd = dl - dd;
            v[j] = (ci < 3 && kd >= 0 && kd < 3)
                 ? f2bf(wg[ch * 81 + ci * 27 + kd * 9 + kh * 3 + kw]) : (short)0;
        }
        ((short8*)wtab)[f * 64 + lane] = v;
    }
    if (t < 32) {
        float s = 0.f;
        #pragma unroll
        for (int cc = 0; cc < 16; ++cc) s += biasg[cc];
        out[t] = s;   // conv blocks atomicAdd on top
    }
}

__global__ __launch_bounds__(256, 8) void fused_conv_pool_reduce(
    const float* __restrict__ xg,    // f32 [32][3][32][128][128]
    const short* __restrict__ wtab,  // bf16 frag table in d_ws
    const float* __restrict__ cbg,   // f32 [16]
    float* __restrict__ out)         // f32 [32]
{
    __shared__ __align__(16) short rawT[2 * 66 * 64];  // 16,896 B (2 buffers)
    __shared__ float wsums[4];

    // XCD-aware bijective swizzle: 4032 = 8 XCDs x 504.
    const int lin = blockIdx.y * 63 + blockIdx.x;      // 0..4031
    const int nl  = (lin & 7) * 504 + (lin >> 3);
    const int hp  = nl % 63;
    const int yy  = nl / 63;       // 0..63
    const int ws  = yy & 1;        // w half
    const int b   = yy >> 1;       // batch
    const int wbase = ws * 64;

    const int tid = threadIdx.x;  // 0..255
    const int lane = tid & 63;
    const int wv   = tid >> 6;    // wave = 16-wide w tile (0..3)
    const int hs   = lane >> 5;

    // ---- resident B-frags (36 VGPR), conv-bias, validity masks ----
    short8 af[9];
    #pragma unroll
    for (int f = 0; f < 9; ++f) af[f] = ((const short8*)wtab)[f * 64 + lane];
    const float cbv = cbg[(lane >> 1) & 15];   // ch = (lane&31)>>1
    float maskA[4];
    #pragma unroll
    for (int a = 0; a < 4; ++a) {
        const bool ok = ((lane & 1) == 0) && (ws * 32 + wv * 8 + 2 * a + hs <= 62);
        maskA[a] = ok ? 1.0f : 0.0f;
    }

    // ---- ws=1: zero halo rows 64,65 of both buffers (never staged there) ----
    if (ws && tid < 64)
        *(unsigned long long*)((char*)rawT + (tid >> 5) * BUFSZ + 8192 + (tid & 31) * 8) = 0ULL;

    #define SWZ(r) (((r) ^ ((r) >> 3)) & 7)

    // ---- per-iter stage map: 2 planes (pair), 2 rows x 8B per thread ----
    const int w4 = tid & 31, dr2 = (tid >> 5) & 1, hr2 = (tid >> 6) & 3;
    int wad[2];
    #pragma unroll
    for (int j = 0; j < 2; ++j) {
        const int row = 2 * w4 + j;
        wad[j] = row * 128 + ((hr2 * 2) ^ SWZ(row)) * 16 + dr2 * 8;
    }

    // ---- halo staging identity (ws=0, 16 threads): rows 64,65 ----
    const bool haloT = (ws == 0) && (tid < 16);
    const int hrow = 64 + (tid & 1);
    const int hlh  = (tid >> 1) & 3;
    const int pah  = (tid >> 3) & 1;      // plane parity within pair
    const int hwad = hrow * 128 + ((hlh * 2) ^ SWZ(hrow)) * 16 + pah * 8;
    const float* hb = xg + (size_t)b * 96 * 16384 + (2 * hp + hlh) * 128 + 64 + (tid & 1);

    // ---- read map: row = wv*16 + wi + kw, chunk = (hh+kh)*2 + hs ----
    const int wi = (lane >> 1) & 15, hh = lane & 1;
    int rad[3][3];
    #pragma unroll
    for (int kh = 0; kh < 3; ++kh) {
        #pragma unroll
        for (int kw = 0; kw < 3; ++kw) {
            const int row = wv * 16 + wi + kw;
            const int phys = ((hh + kh) * 2 + hs) ^ SWZ(row);
            rad[kh][kw] = row * 128 + phys * 16;
        }
    }

    // ---- prologue: stage pairs 0,1 (planes 0..3), rows 0..63, buffer 0 ----
    {
        const int w4p = tid & 15, drp = (tid >> 4) & 3, hrp = (tid >> 6) & 3;
        const float* srcP = xg + ((size_t)b * 96 + drp) * 16384
                          + (2 * hp + hrp) * 128 + wbase + 4 * w4p;
        const floatx4 c0 = *(const floatx4*)(srcP);
        const floatx4 c1 = *(const floatx4*)(srcP + 524288);
        const floatx4 c2 = *(const floatx4*)(srcP + 1048576);
        const int chunkL = hrp * 2 + (drp >> 1);
        const int parP   = (drp & 1) * 8;
        #pragma unroll
        for (int i = 0; i < 4; ++i) {
            const int row = 4 * w4p + i;
            const int ad = row * 128 + (chunkL ^ SWZ(row)) * 16 + parP;
            uint2 pk;
            pk.x = pkbf2(c0[i], c1[i]);
            pk.y = pkbf2(c2[i], 0.0f);
            *(uint2*)((char*)rawT + ad) = pk;
        }
    }
    // prologue halo: rows 64,65 x 4 hl x planes 0..3 (ws=0 only, 32 threads)
    if (ws == 0 && tid < 32) {
        const int row = 64 + (tid & 1), hl = (tid >> 1) & 3, dpl = (tid >> 3) & 3;
        const float* p = xg + ((size_t)b * 96 + dpl) * 16384 + (2 * hp + hl) * 128 + 64 + (tid & 1);
        const float f0 = p[0], f1 = p[524288], f2 = p[1048576];
        const int ad = row * 128 + (((hl * 2) + (dpl >> 1)) ^ SWZ(row)) * 16 + (dpl & 1) * 8;
        uint2 pk;
        pk.x = pkbf2(f0, f1);
        pk.y = pkbf2(f2, 0.0f);
        *(uint2*)((char*)rawT + ad) = pk;
    }

    // ---- prefetch pair 2 (planes 4,5): float2 per ci; halo: 3 scalars ----
    const float* src2 = xg + ((size_t)b * 96 + 4 + dr2) * 16384
                      + (2 * hp + hr2) * 128 + wbase + 2 * w4;
    floatx2 A0 = *(const floatx2*)(src2);
    floatx2 A1 = *(const floatx2*)(src2 + 524288);
    floatx2 A2 = *(const floatx2*)(src2 + 1048576);
    float h0 = 0.f, h1 = 0.f, h2 = 0.f;
    if (haloT) {
        const float* p = hb + (size_t)(4 + pah) * 16384;
        h0 = p[0]; h1 = p[524288]; h2 = p[1048576];
    }

    float vsum = 0.f;
    for (int dp = 0; dp < 15; ++dp) {
        const int p16 = (dp & 1) << 4;
        if (dp <= 13) {
            // stage pair dp+2 into buffer ((dp>>1)+1)&1, chunk-parity = dp&1
            const int bw = (((dp >> 1) + 1) & 1) * BUFSZ;
            uint2 pk0, pk1;
            pk0.x = pkbf2(A0[0], A1[0]); pk0.y = pkbf2(A2[0], 0.0f);
            pk1.x = pkbf2(A0[1], A1[1]); pk1.y = pkbf2(A2[1], 0.0f);
            *(uint2*)((char*)rawT + bw + (wad[0] ^ p16)) = pk0;
            *(uint2*)((char*)rawT + bw + (wad[1] ^ p16)) = pk1;
            if (haloT) {
                uint2 hpk;
                hpk.x = pkbf2(h0, h1); hpk.y = pkbf2(h2, 0.0f);
                *(uint2*)((char*)rawT + bw + (hwad ^ p16)) = hpk;
            }
            if (dp <= 12) {     // prefetch pair dp+3 (full-iter latency cover)
                src2 += 32768;
                A0 = *(const floatx2*)(src2);
                A1 = *(const floatx2*)(src2 + 524288);
                A2 = *(const floatx2*)(src2 + 1048576);
                if (haloT) {
                    const float* p = hb + (size_t)(2 * dp + 6 + pah) * 16384;
                    h0 = p[0]; h1 = p[524288]; h2 = p[1048576];
                }
            }
        }
        BAR();   // LDS-only; global loads stay in flight

        // read buffer per lane-half: pair (dp+hs) -> buffer ((dp+hs)>>1)&1
        const int roff = (((dp + hs) >> 1) & 1) * BUFSZ;

        floatx16 acc = {0.f,0.f,0.f,0.f,0.f,0.f,0.f,0.f,
                        0.f,0.f,0.f,0.f,0.f,0.f,0.f,0.f};
        #pragma unroll
        for (int kh = 0; kh < 3; ++kh) {
            #pragma unroll
            for (int kw = 0; kw < 3; ++kw) {
                const short8 bf = *(const short8*)((char*)rawT + roff + (rad[kh][kw] ^ p16));
                acc = __builtin_amdgcn_mfma_f32_32x32x16_bf16(bf, af[kh * 3 + kw], acc, 0, 0, 0);
            }
        }
        // epilogue: acc[4a..4a+3] = one 2x2 h/w window (in-reg max),
        // dd-pool = DPP ^1, then +cb, relu, masked accumulate.
        #pragma unroll
        for (int a = 0; a < 4; ++a) {
            float m01 = fmaxf(acc[4 * a],     acc[4 * a + 1]);
            float m23 = fmaxf(acc[4 * a + 2], acc[4 * a + 3]);
            float m   = fmaxf(m01, m23);
            m = dpp_max<0xB1>(m);                 // pool over dd (lane ^ 1)
            const float v = fmaxf(m + cbv, 0.f);  // +conv_b, relu (post-pool)
            vsum = fmaf(maskA[a], v, vsum);
        }
    }

    // mask already zeroes invalid lanes/groups: plain full-wave sum
    float s = vsum;
    #pragma unroll
    for (int off = 1; off < 64; off <<= 1) s += __shfl_xor(s, off, 64);

    if (lane == 0) wsums[wv] = s;
    __syncthreads();
    if (tid == 0) {
        float bs = 0.f;
        #pragma unroll
        for (int i = 0; i < 4; ++i) bs += wsums[i];
        atomicAdd(&out[b], bs * (1.0f / 119070.0f));   // /(15*63*63)/2
    }
}

extern "C" void kernel_launch(void* const* d_in, const int* in_sizes, int n_in,
                              void* d_out, int out_size, void* d_ws, size_t ws_size,
                              hipStream_t stream) {
    const float* x      = (const float*)d_in[0];
    const float* conv_w = (const float*)d_in[1];
    const float* conv_b = (const float*)d_in[2];
    const float* bias   = (const float*)d_in[3];
    float* out = (float*)d_out;
    short* wtab = (short*)d_ws;   // 9216 B

    init_kernel<<<1, 576, 0, stream>>>(conv_w, bias, wtab, out);
    dim3 grid(63, 64);  // (hp, ws|b) pre-swizzle
    fused_conv_pool_reduce<<<grid, 256, 0, stream>>>(x, wtab, conv_b, out);
}

// Round 7
// 287.933 us; speedup vs baseline: 1.9040x; 1.9040x over previous
//
#include <hip/hip_runtime.h>
#include <hip/hip_bf16.h>

// Fused Conv3d(3->16,k=3,valid) + conv_b + ReLU + maxpool2x2x2
// + spatial mean(fp32) + /2 + bias + channel-sum  ->  out[32] fp32.
//
// R16: R15 retried without the spill. R15's __launch_bounds__(256,8) capped
// VGPR at 64 < the ~80 needed -> full spill (WRITE_SIZE 63KB->145MB, FETCH
// x5, VGPR_Count 32, kernel became scratch-BW-bound at 357us). Same code
// with __launch_bounds__(256,4): VGPR cap 128, no spills, ~4 waves/SIMD ->
// 4 independent 256-thread blocks/CU (2x R12's barrier groups; 8 if regs
// land <=64). Tests the phase-overlap hypothesis cleanly.
//  - block = (hp, ws, b): w-range split in half, 4 waves, LDS 2 x 8448 B.
//  - ws=0 stages halo rows 64,65 (16 threads, 3 scalars each); ws=1 zeroes
//    them once (they only reach masked outputs). Mask gains ws*32 term.
//  - XCD bijective swizzle: 4032 = 8 x 504.
// (R12 core, verified absmax=0 three times): operand-swapped MFMA
//  (M=spatial, N=(ch,dd)), in-register 2x2 pool + DPP dd-pool, d-plane
//  rotation (stage 2 planes/iter, parity ^16, hs-split buffer), ci-fast
//  packing, XOR bank swizzle, lgkm-only BAR (globals stay in flight).
//  MFMA m32n32k16, D: col=lane&31, row=(reg&3)+8*(reg>>2)+4*(lane>>5).

typedef __attribute__((ext_vector_type(8)))  short  short8;
typedef __attribute__((ext_vector_type(2)))  float  floatx2;
typedef __attribute__((ext_vector_type(4)))  float  floatx4;
typedef __attribute__((ext_vector_type(16))) float  floatx16;

__device__ __forceinline__ short f2bf(float f) {
    unsigned u = __builtin_bit_cast(unsigned, f);
    unsigned r = (u + 0x7FFFu + ((u >> 16) & 1u)) >> 16;
    return (short)r;
}

__device__ __forceinline__ unsigned pkbf2(float a, float b) {
    __hip_bfloat162 h = __float22bfloat162_rn(float2{a, b});  // v_cvt_pk_bf16_f32
    unsigned r;
    __builtin_memcpy(&r, &h, 4);
    return r;
}

template <int CTRL>
__device__ __forceinline__ float dpp_max(float v) {
    int x = __builtin_bit_cast(int, v);
    int y = __builtin_amdgcn_mov_dpp(x, CTRL, 0xF, 0xF, true);
    return fmaxf(v, __builtin_bit_cast(float, y));
}

// LDS-only barrier: drain DS ops, leave global loads in flight (no vmcnt).
#define BAR() asm volatile("s_waitcnt lgkmcnt(0)\n\ts_barrier" ::: "memory")

#define BUFSZ 8448   // 66 rows x 128 B

// ---- init: wtab[f=kh*3+kw][lane][8] zero-padded B-frags + out = bias sums ----
__global__ void init_kernel(const float* __restrict__ wg,
                            const float* __restrict__ biasg,
                            short* __restrict__ wtab,   // d_ws: 9*64*8 bf16 = 9216 B
                            float* __restrict__ out)    // [32]
{
    const int t = threadIdx.x;               // 0..575
    if (t < 576) {
        const int lane = t & 63, f = t >> 6;
        const int kh = f / 3, kw = f % 3;
        const int m = lane & 31, hs = lane >> 5;
        const int ch = m >> 1, dd = m & 1;   // col = 2*ch + dd
        short8 v;
        #pragma unroll
        for (int j = 0; j < 8; ++j) {
            const int s = hs * 8 + j;        // k-slot: dl_rel = s>>2, ci = s&3
            const int dl = s >> 2, ci = s & 3;
            const int kd = dl - dd;
            v[j] = (ci < 3 && kd >= 0 && kd < 3)
                 ? f2bf(wg[ch * 81 + ci * 27 + kd * 9 + kh * 3 + kw]) : (short)0;
        }
        ((short8*)wtab)[f * 64 + lane] = v;
    }
    if (t < 32) {
        float s = 0.f;
        #pragma unroll
        for (int cc = 0; cc < 16; ++cc) s += biasg[cc];
        out[t] = s;   // conv blocks atomicAdd on top
    }
}

__global__ __launch_bounds__(256, 4) void fused_conv_pool_reduce(
    const float* __restrict__ xg,    // f32 [32][3][32][128][128]
    const short* __restrict__ wtab,  // bf16 frag table in d_ws
    const float* __restrict__ cbg,   // f32 [16]
    float* __restrict__ out)         // f32 [32]
{
    __shared__ __align__(16) short rawT[2 * 66 * 64];  // 16,896 B (2 buffers)
    __shared__ float wsums[4];

    // XCD-aware bijective swizzle: 4032 = 8 XCDs x 504.
    const int lin = blockIdx.y * 63 + blockIdx.x;      // 0..4031
    const int nl  = (lin & 7) * 504 + (lin >> 3);
    const int hp  = nl % 63;
    const int yy  = nl / 63;       // 0..63
    const int ws  = yy & 1;        // w half
    const int b   = yy >> 1;       // batch
    const int wbase = ws * 64;

    const int tid = threadIdx.x;  // 0..255
    const int lane = tid & 63;
    const int wv   = tid >> 6;    // wave = 16-wide w tile (0..3)
    const int hs   = lane >> 5;

    // ---- resident B-frags (36 VGPR), conv-bias, validity masks ----
    short8 af[9];
    #pragma unroll
    for (int f = 0; f < 9; ++f) af[f] = ((const short8*)wtab)[f * 64 + lane];
    const float cbv = cbg[(lane >> 1) & 15];   // ch = (lane&31)>>1
    float maskA[4];
    #pragma unroll
    for (int a = 0; a < 4; ++a) {
        const bool ok = ((lane & 1) == 0) && (ws * 32 + wv * 8 + 2 * a + hs <= 62);
        maskA[a] = ok ? 1.0f : 0.0f;
    }

    // ---- ws=1: zero halo rows 64,65 of both buffers (never staged there) ----
    if (ws && tid < 64)
        *(unsigned long long*)((char*)rawT + (tid >> 5) * BUFSZ + 8192 + (tid & 31) * 8) = 0ULL;

    #define SWZ(r) (((r) ^ ((r) >> 3)) & 7)

    // ---- per-iter stage map: 2 planes (pair), 2 rows x 8B per thread ----
    const int w4 = tid & 31, dr2 = (tid >> 5) & 1, hr2 = (tid >> 6) & 3;
    int wad[2];
    #pragma unroll
    for (int j = 0; j < 2; ++j) {
        const int row = 2 * w4 + j;
        wad[j] = row * 128 + ((hr2 * 2) ^ SWZ(row)) * 16 + dr2 * 8;
    }

    // ---- halo staging identity (ws=0, 16 threads): rows 64,65 ----
    const bool haloT = (ws == 0) && (tid < 16);
    const int hrow = 64 + (tid & 1);
    const int hlh  = (tid >> 1) & 3;
    const int pah  = (tid >> 3) & 1;      // plane parity within pair
    const int hwad = hrow * 128 + ((hlh * 2) ^ SWZ(hrow)) * 16 + pah * 8;
    const float* hb = xg + (size_t)b * 96 * 16384 + (2 * hp + hlh) * 128 + 64 + (tid & 1);

    // ---- read map: row = wv*16 + wi + kw, chunk = (hh+kh)*2 + hs ----
    const int wi = (lane >> 1) & 15, hh = lane & 1;
    int rad[3][3];
    #pragma unroll
    for (int kh = 0; kh < 3; ++kh) {
        #pragma unroll
        for (int kw = 0; kw < 3; ++kw) {
            const int row = wv * 16 + wi + kw;
            const int phys = ((hh + kh) * 2 + hs) ^ SWZ(row);
            rad[kh][kw] = row * 128 + phys * 16;
        }
    }

    // ---- prologue: stage pairs 0,1 (planes 0..3), rows 0..63, buffer 0 ----
    {
        const int w4p = tid & 15, drp = (tid >> 4) & 3, hrp = (tid >> 6) & 3;
        const float* srcP = xg + ((size_t)b * 96 + drp) * 16384
                          + (2 * hp + hrp) * 128 + wbase + 4 * w4p;
        const floatx4 c0 = *(const floatx4*)(srcP);
        const floatx4 c1 = *(const floatx4*)(srcP + 524288);
        const floatx4 c2 = *(const floatx4*)(srcP + 1048576);
        const int chunkL = hrp * 2 + (drp >> 1);
        const int parP   = (drp & 1) * 8;
        #pragma unroll
        for (int i = 0; i < 4; ++i) {
            const int row = 4 * w4p + i;
            const int ad = row * 128 + (chunkL ^ SWZ(row)) * 16 + parP;
            uint2 pk;
            pk.x = pkbf2(c0[i], c1[i]);
            pk.y = pkbf2(c2[i], 0.0f);
            *(uint2*)((char*)rawT + ad) = pk;
        }
    }
    // prologue halo: rows 64,65 x 4 hl x planes 0..3 (ws=0 only, 32 threads)
    if (ws == 0 && tid < 32) {
        const int row = 64 + (tid & 1), hl = (tid >> 1) & 3, dpl = (tid >> 3) & 3;
        const float* p = xg + ((size_t)b * 96 + dpl) * 16384 + (2 * hp + hl) * 128 + 64 + (tid & 1);
        const float f0 = p[0], f1 = p[524288], f2 = p[1048576];
        const int ad = row * 128 + (((hl * 2) + (dpl >> 1)) ^ SWZ(row)) * 16 + (dpl & 1) * 8;
        uint2 pk;
        pk.x = pkbf2(f0, f1);
        pk.y = pkbf2(f2, 0.0f);
        *(uint2*)((char*)rawT + ad) = pk;
    }

    // ---- prefetch pair 2 (planes 4,5): float2 per ci; halo: 3 scalars ----
    const float* src2 = xg + ((size_t)b * 96 + 4 + dr2) * 16384
                      + (2 * hp + hr2) * 128 + wbase + 2 * w4;
    floatx2 A0 = *(const floatx2*)(src2);
    floatx2 A1 = *(const floatx2*)(src2 + 524288);
    floatx2 A2 = *(const floatx2*)(src2 + 1048576);
    float h0 = 0.f, h1 = 0.f, h2 = 0.f;
    if (haloT) {
        const float* p = hb + (size_t)(4 + pah) * 16384;
        h0 = p[0]; h1 = p[524288]; h2 = p[1048576];
    }

    float vsum = 0.f;
    for (int dp = 0; dp < 15; ++dp) {
        const int p16 = (dp & 1) << 4;
        if (dp <= 13) {
            // stage pair dp+2 into buffer ((dp>>1)+1)&1, chunk-parity = dp&1
            const int bw = (((dp >> 1) + 1) & 1) * BUFSZ;
            uint2 pk0, pk1;
            pk0.x = pkbf2(A0[0], A1[0]); pk0.y = pkbf2(A2[0], 0.0f);
            pk1.x = pkbf2(A0[1], A1[1]); pk1.y = pkbf2(A2[1], 0.0f);
            *(uint2*)((char*)rawT + bw + (wad[0] ^ p16)) = pk0;
            *(uint2*)((char*)rawT + bw + (wad[1] ^ p16)) = pk1;
            if (haloT) {
                uint2 hpk;
                hpk.x = pkbf2(h0, h1); hpk.y = pkbf2(h2, 0.0f);
                *(uint2*)((char*)rawT + bw + (hwad ^ p16)) = hpk;
            }
            if (dp <= 12) {     // prefetch pair dp+3 (full-iter latency cover)
                src2 += 32768;
                A0 = *(const floatx2*)(src2);
                A1 = *(const floatx2*)(src2 + 524288);
                A2 = *(const floatx2*)(src2 + 1048576);
                if (haloT) {
                    const float* p = hb + (size_t)(2 * dp + 6 + pah) * 16384;
                    h0 = p[0]; h1 = p[524288]; h2 = p[1048576];
                }
            }
        }
        BAR();   // LDS-only; global loads stay in flight

        // read buffer per lane-half: pair (dp+hs) -> buffer ((dp+hs)>>1)&1
        const int roff = (((dp + hs) >> 1) & 1) * BUFSZ;

        floatx16 acc = {0.f,0.f,0.f,0.f,0.f,0.f,0.f,0.f,
                        0.f,0.f,0.f,0.f,0.f,0.f,0.f,0.f};
        #pragma unroll
        for (int kh = 0; kh < 3; ++kh) {
            #pragma unroll
            for (int kw = 0; kw < 3; ++kw) {
                const short8 bf = *(const short8*)((char*)rawT + roff + (rad[kh][kw] ^ p16));
                acc = __builtin_amdgcn_mfma_f32_32x32x16_bf16(bf, af[kh * 3 + kw], acc, 0, 0, 0);
            }
        }
        // epilogue: acc[4a..4a+3] = one 2x2 h/w window (in-reg max),
        // dd-pool = DPP ^1, then +cb, relu, masked accumulate.
        #pragma unroll
        for (int a = 0; a < 4; ++a) {
            float m01 = fmaxf(acc[4 * a],     acc[4 * a + 1]);
            float m23 = fmaxf(acc[4 * a + 2], acc[4 * a + 3]);
            float m   = fmaxf(m01, m23);
            m = dpp_max<0xB1>(m);                 // pool over dd (lane ^ 1)
            const float v = fmaxf(m + cbv, 0.f);  // +conv_b, relu (post-pool)
            vsum = fmaf(maskA[a], v, vsum);
        }
    }

    // mask already zeroes invalid lanes/groups: plain full-wave sum
    float s = vsum;
    #pragma unroll
    for (int off = 1; off < 64; off <<= 1) s += __shfl_xor(s, off, 64);

    if (lane == 0) wsums[wv] = s;
    __syncthreads();
    if (tid == 0) {
        float bs = 0.f;
        #pragma unroll
        for (int i = 0; i < 4; ++i) bs += wsums[i];
        atomicAdd(&out[b], bs * (1.0f / 119070.0f));   // /(15*63*63)/2
    }
}

extern "C" void kernel_launch(void* const* d_in, const int* in_sizes, int n_in,
                              void* d_out, int out_size, void* d_ws, size_t ws_size,
                              hipStream_t stream) {
    const float* x      = (const float*)d_in[0];
    const float* conv_w = (const float*)d_in[1];
    const float* conv_b = (const float*)d_in[2];
    const float* bias   = (const float*)d_in[3];
    float* out = (float*)d_out;
    short* wtab = (short*)d_ws;   // 9216 B

    init_kernel<<<1, 576, 0, stream>>>(conv_w, bias, wtab, out);
    dim3 grid(63, 64);  // (hp, ws|b) pre-swizzle
    fused_conv_pool_reduce<<<grid, 256, 0, stream>>>(x, wtab, conv_b, out);
}